// Round 15
// baseline (1070.842 us; speedup 1.0000x reference)
//
#include <hip/hip_runtime.h>

#define N_ 1024
#define D_ 128
#define K_ 256
#define M_ 4
#define H_ 256
#define NB_ 2
#define KT_ 64
#define NTILE_ 4
#define EPS_ 0.12f
#define CHPAD 136     // u16 stride for Chi/Clo views
#define CFS 140       // f32 stride for Cf view (bank-spread)
#define HPAD  264     // u16 stride for H rows

typedef _Float16 half8 __attribute__((ext_vector_type(8)));
typedef __attribute__((ext_vector_type(8))) short short8;
typedef __attribute__((ext_vector_type(4))) float f32x4;
typedef __attribute__((ext_vector_type(16))) float f32x16;

__device__ inline float s2f(unsigned short s) {
    return (float)__builtin_bit_cast(_Float16, s);
}
__device__ inline unsigned short f2h(float x) {
    return __builtin_bit_cast(unsigned short, (_Float16)x);
}
__device__ inline void split2h(float x, unsigned short& hi, unsigned short& lo) {
    _Float16 h = (_Float16)x;
    _Float16 l = (_Float16)(x - (float)h);
    hi = __builtin_bit_cast(unsigned short, h);
    lo = __builtin_bit_cast(unsigned short, l);
}
__device__ inline f32x16 zero16() {
    f32x16 v;
    #pragma unroll
    for (int i = 0; i < 16; ++i) v[i] = 0.0f;
    return v;
}
// LDS-only barrier: wait LDS ops, sync, leave global loads in flight.
__device__ inline void lds_barrier() {
    asm volatile("s_waitcnt lgkmcnt(0)" ::: "memory");
    __builtin_amdgcn_sched_barrier(0);
    __builtin_amdgcn_s_barrier();
    __builtin_amdgcn_sched_barrier(0);
}

// ---------------------------------------------------------------------------
// Bb (row layout, for refine) + Bbpk (GEMM2-fragment order, for C-init).
// Bbpk idx: ((((m*4+tile)*4+wid)*8+run)*64+lane)*4+j
//   lane=(hi<<5)|l31 -> d=wid*32+l31, k=tile*64+32*(run>>2)+8*(run&3)+4*hi+j
// ---------------------------------------------------------------------------
__global__ void precompute_Bb(const float* __restrict__ base_cb,
                              const float* __restrict__ cp_w,
                              float* __restrict__ Bb,
                              float* __restrict__ Bbpk) {
    const int mk = blockIdx.x;
    const int m  = mk >> 8;
    const int k  = mk & 255;
    const int d  = threadIdx.x;
    const float* cb = base_cb + (size_t)mk * D_;
    const float* wc = cp_w + ((size_t)(m * D_ + d)) * (2 * D_) + D_;
    double a0 = 0, a1 = 0, a2 = 0, a3 = 0;
    #pragma unroll
    for (int dp = 0; dp < D_; dp += 4) {
        a0 += (double)(cb[dp + 0] * wc[dp + 0]);
        a1 += (double)(cb[dp + 1] * wc[dp + 1]);
        a2 += (double)(cb[dp + 2] * wc[dp + 2]);
        a3 += (double)(cb[dp + 3] * wc[dp + 3]);
    }
    const float v = (float)((a0 + a1) + (a2 + a3));
    Bb[(size_t)mk * D_ + d] = v;

    const int tile = k >> 6, rr = k & 63;
    const int cg = rr >> 5, rr2 = rr & 31;
    const int q = rr2 >> 3, hi = (rr2 >> 2) & 1, j = rr2 & 3;
    const int run = (cg << 2) | q;
    const int lane = (hi << 5) | (d & 31);
    const int wid = d >> 5;
    const size_t idx = ((((size_t)m * 4 + tile) * 4 + wid) * 8 + run) * 256 + lane * 4 + j;
    Bbpk[idx] = v;
}

// ---------------------------------------------------------------------------
// Pack single-f16 weights into wave-coalesced fragment order.
// ---------------------------------------------------------------------------
__global__ void convert_w(const float* __restrict__ w1,
                          const float* __restrict__ w2,
                          unsigned short* __restrict__ w1pk,
                          unsigned short* __restrict__ w2pk) {
    const int i = blockIdx.x * blockDim.x + threadIdx.x;  // 0..262143
    {
        const int e    = i & 7;
        const int sel  = (i >> 3) & 1;
        const int j32  = (i >> 4) & 31;
        const int kt   = (i >> 9) & 7;
        const int jblk = (i >> 12) & 7;
        const int bi   = i >> 15;
        const int j = jblk * 32 + j32;
        const int d = kt * 16 + sel * 8 + e;
        w1pk[i] = f2h(w1[((size_t)(bi * H_ + j)) * D_ + d]);
    }
    {
        const int e    = i & 7;
        const int sel  = (i >> 3) & 1;
        const int d32  = (i >> 4) & 31;
        const int s    = (i >> 9) & 15;
        const int dblk = (i >> 13) & 3;
        const int bi   = i >> 15;
        const int d = dblk * 32 + d32;
        const int hc = s * 16 + sel * 8 + e;
        w2pk[i] = f2h(w2[((size_t)(bi * D_ + d)) * H_ + hc]);
    }
}

// ---------------------------------------------------------------------------
// mega kernel: one block per n; entire M-loop; C carried in registers in the
// MFMA C/D fragment layout; LDS holds only the hi/lo split for GEMM1 + f32 C
// for the dist phase (union buffer).
// ---------------------------------------------------------------------------
__launch_bounds__(256, 2)
__global__ void mega_kernel(const float* __restrict__ z,
                            const float* __restrict__ cp_w,
                            const float* __restrict__ cp_b,
                            const float* __restrict__ w1,
                            const float* __restrict__ b1,
                            const float* __restrict__ w2,
                            const float* __restrict__ b2,
                            const float* __restrict__ Bb,
                            const float* __restrict__ Bbpk,
                            const unsigned short* __restrict__ w1pk,
                            const unsigned short* __restrict__ w2pk,
                            float* __restrict__ out0,
                            float* __restrict__ out1,
                            float* __restrict__ out2,
                            float* __restrict__ out3) {
    __shared__ alignas(16) char sCbuf[35840];   // u16 Chi/Clo view OR f32 Cf view
    __shared__ alignas(16) unsigned short sHh[KT_][HPAD];
    __shared__ alignas(16) float sA[D_], sxhat[D_], sr[D_], scb[D_];
    __shared__ alignas(16) float sdist[K_];
    __shared__ float sE[D_], scsel[D_];
    __shared__ float shrow[H_];
    __shared__ double sdd[2];
    __shared__ float smin, sbest;
    __shared__ int   sbidx, supd;

    #define CHI(r, c) (((unsigned short*)sCbuf)[(r) * CHPAD + (c)])
    #define CLO(r, c) (((unsigned short*)sCbuf)[8704 + (r) * CHPAD + (c)])
    #define CF(r, c)  (((float*)sCbuf)[(r) * CFS + (c)])

    const int n    = blockIdx.x;
    const int t    = threadIdx.x;
    const int wid  = t >> 6;
    const int lane = t & 63;
    const int l31  = lane & 31;
    const int hi   = lane >> 5;
    const int koff = hi * 8;
    const int loff = (l31 * 2 + hi) * 8;
    const int dcol = wid * 32 + l31;

    if (t < D_) { sxhat[t] = 0.0f; sA[t] = 0.0f; }
    __syncthreads();

    for (int m = 0; m < M_; ++m) {
        if (t < D_) {
            scb[t] = cp_b[m * D_ + t];
            const float rv = z[(size_t)n * D_ + t] - sxhat[t];
            sr[t] = rv;
            out2[((size_t)m * N_ + n) * D_ + t] = rv;
        }
        lds_barrier();
        const float aD  = sA[dcol];
        const float cbD = scb[dcol];

        // ================= fast path: 4 tiles of 64 codewords ==============
        for (int tile = 0; tile < NTILE_; ++tile) {
            const int k0 = tile * KT_;

            // ---- C init: cr regs in fragment layout + hi/lo split to LDS ----
            f32x16 cr0, cr1;
            {
                const float* bbp = Bbpk +
                    ((((size_t)m * 4 + tile) * 4 + wid) * 8) * 256 + lane * 4;
                #pragma unroll
                for (int run = 0; run < 4; ++run) {
                    const f32x4 b0 = *(const f32x4*)(bbp + run * 256);
                    const f32x4 b1 = *(const f32x4*)(bbp + (run + 4) * 256);
                    #pragma unroll
                    for (int j = 0; j < 4; ++j) {
                        cr0[run * 4 + j] = (aD + b0[j]) + cbD;
                        cr1[run * 4 + j] = (aD + b1[j]) + cbD;
                    }
                }
                #pragma unroll
                for (int reg = 0; reg < 16; ++reg) {
                    const int krow = (reg & 3) + 8 * (reg >> 2) + 4 * hi;
                    unsigned short ch, cl;
                    split2h(cr0[reg], ch, cl);
                    CHI(krow, dcol) = ch; CLO(krow, dcol) = cl;
                    split2h(cr1[reg], ch, cl);
                    CHI(32 + krow, dcol) = ch; CLO(32 + krow, dcol) = cl;
                }
            }
            lds_barrier();

            for (int i = 0; i < NB_; ++i) {
                const int bi = m * NB_ + i;

                // ---- GEMM1 (2-pass): h = relu(C @ W1^T + b1) ----
                half8 g2w[16];
                {
                    const int j0 = wid * 32 + l31;
                    const unsigned short* pA = w1pk + ((size_t)((bi * 8 + wid) * 8)) * 512 + loff;
                    const unsigned short* pB = w1pk + ((size_t)((bi * 8 + wid + 4) * 8)) * 512 + loff;
                    half8 wA[8], wB[8];
                    #pragma unroll
                    for (int kt = 0; kt < 8; ++kt) {
                        wA[kt] = *(const half8*)(pA + kt * 512);
                        wB[kt] = *(const half8*)(pB + kt * 512);
                    }
                    f32x16 aA0 = zero16(), aA1 = zero16();
                    f32x16 aB0 = zero16(), aB1 = zero16();
                    #pragma unroll
                    for (int kt = 0; kt < 8; ++kt) {
                        half8 ah0 = *(const half8*)&CHI(l31, kt * 16 + koff);
                        half8 al0 = *(const half8*)&CLO(l31, kt * 16 + koff);
                        half8 ah1 = *(const half8*)&CHI(32 + l31, kt * 16 + koff);
                        half8 al1 = *(const half8*)&CLO(32 + l31, kt * 16 + koff);
                        aA0 = __builtin_amdgcn_mfma_f32_32x32x16_f16(ah0, wA[kt], aA0, 0, 0, 0);
                        aB0 = __builtin_amdgcn_mfma_f32_32x32x16_f16(ah0, wB[kt], aB0, 0, 0, 0);
                        aA1 = __builtin_amdgcn_mfma_f32_32x32x16_f16(ah1, wA[kt], aA1, 0, 0, 0);
                        aB1 = __builtin_amdgcn_mfma_f32_32x32x16_f16(ah1, wB[kt], aB1, 0, 0, 0);
                        aA0 = __builtin_amdgcn_mfma_f32_32x32x16_f16(al0, wA[kt], aA0, 0, 0, 0);
                        aB0 = __builtin_amdgcn_mfma_f32_32x32x16_f16(al0, wB[kt], aB0, 0, 0, 0);
                        aA1 = __builtin_amdgcn_mfma_f32_32x32x16_f16(al1, wA[kt], aA1, 0, 0, 0);
                        aB1 = __builtin_amdgcn_mfma_f32_32x32x16_f16(al1, wB[kt], aB1, 0, 0, 0);
                    }
                    // prefetch GEMM2 weights (survive the LDS barrier)
                    {
                        const unsigned short* pd =
                            w2pk + ((size_t)((bi * 4 + wid) * 16)) * 512 + loff;
                        #pragma unroll
                        for (int s = 0; s < 16; ++s)
                            g2w[s] = *(const half8*)(pd + s * 512);
                    }
                    const float b1A = b1[(size_t)bi * H_ + j0];
                    const float b1B = b1[(size_t)bi * H_ + j0 + 128];
                    #pragma unroll
                    for (int reg = 0; reg < 16; ++reg) {
                        const int krow = (reg & 3) + 8 * (reg >> 2) + 4 * hi;
                        sHh[krow][j0]            = f2h(fmaxf(aA0[reg] + b1A, 0.0f));
                        sHh[32 + krow][j0]       = f2h(fmaxf(aA1[reg] + b1A, 0.0f));
                        sHh[krow][j0 + 128]      = f2h(fmaxf(aB0[reg] + b1B, 0.0f));
                        sHh[32 + krow][j0 + 128] = f2h(fmaxf(aB1[reg] + b1B, 0.0f));
                    }
                }
                lds_barrier();

                // ---- GEMM2 (1-pass), acc seeded with C regs ----
                {
                    f32x16 c0a = cr0, c0b = zero16();
                    f32x16 c1a = cr1, c1b = zero16();
                    #pragma unroll
                    for (int s = 0; s < 16; s += 2) {
                        half8 h0e = *(const half8*)&sHh[l31][s * 16 + koff];
                        half8 h1e = *(const half8*)&sHh[32 + l31][s * 16 + koff];
                        half8 h0o = *(const half8*)&sHh[l31][(s + 1) * 16 + koff];
                        half8 h1o = *(const half8*)&sHh[32 + l31][(s + 1) * 16 + koff];
                        c0a = __builtin_amdgcn_mfma_f32_32x32x16_f16(h0e, g2w[s], c0a, 0, 0, 0);
                        c1a = __builtin_amdgcn_mfma_f32_32x32x16_f16(h1e, g2w[s], c1a, 0, 0, 0);
                        c0b = __builtin_amdgcn_mfma_f32_32x32x16_f16(h0o, g2w[s + 1], c0b, 0, 0, 0);
                        c1b = __builtin_amdgcn_mfma_f32_32x32x16_f16(h1o, g2w[s + 1], c1b, 0, 0, 0);
                    }
                    const float b2v = b2[(size_t)bi * D_ + dcol];
                    #pragma unroll
                    for (int reg = 0; reg < 16; ++reg) {
                        cr0[reg] = (c0a[reg] + c0b[reg]) + b2v;
                        cr1[reg] = (c1a[reg] + c1b[reg]) + b2v;
                    }
                }
                if (i < NB_ - 1) {
                    #pragma unroll
                    for (int reg = 0; reg < 16; ++reg) {
                        const int krow = (reg & 3) + 8 * (reg >> 2) + 4 * hi;
                        unsigned short ch, cl;
                        split2h(cr0[reg], ch, cl);
                        CHI(krow, dcol) = ch; CLO(krow, dcol) = cl;
                        split2h(cr1[reg], ch, cl);
                        CHI(32 + krow, dcol) = ch; CLO(32 + krow, dcol) = cl;
                    }
                } else {
                    #pragma unroll
                    for (int reg = 0; reg < 16; ++reg) {
                        const int krow = (reg & 3) + 8 * (reg >> 2) + 4 * hi;
                        CF(krow, dcol)      = cr0[reg];
                        CF(32 + krow, dcol) = cr1[reg];
                    }
                }
                lds_barrier();
            }

            // ---- fast dists for this tile (f32 vector reads) ----
            {
                const int row = t >> 2, seg = t & 3, db = seg * 32;
                float qa = 0.f;
                #pragma unroll
                for (int g = 0; g < 8; ++g) {
                    const f32x4 cv = *(const f32x4*)&CF(row, db + g * 4);
                    const f32x4 rv = *(const f32x4*)&sr[db + g * 4];
                    #pragma unroll
                    for (int x = 0; x < 4; ++x) {
                        const float e = rv[x] - cv[x];
                        qa = fmaf(e, e, qa);
                    }
                }
                qa += __shfl_xor(qa, 1);
                qa += __shfl_xor(qa, 2);
                if (seg == 0) sdist[k0 + row] = qa;
            }
            lds_barrier();
        }

        // ================= refine: serial exact f64 candidates =============
        if (t < 64) {
            float bv = fminf(fminf(sdist[t], sdist[t + 64]),
                             fminf(sdist[t + 128], sdist[t + 192]));
            #pragma unroll
            for (int s = 1; s < 64; s <<= 1) bv = fminf(bv, __shfl_xor(bv, s));
            if (t == 0) { smin = bv; sbest = 1e30f; sbidx = 0; }
        }
        __syncthreads();
        const float thr = smin + EPS_;

        for (int k = 0; k < K_; ++k) {
            if (sdist[k] > thr) continue;
            if (t < D_)
                sE[t] = (sA[t] + Bb[((size_t)(m * K_ + k)) * D_ + t]) + scb[t];
            __syncthreads();
            for (int i = 0; i < NB_; ++i) {
                const int bi = m * NB_ + i;
                {
                    const f32x4* wp = (const f32x4*)(w1 + ((size_t)bi * H_ + t) * D_);
                    double h0 = 0, h1 = 0, h2 = 0, h3 = 0;
                    #pragma unroll 8
                    for (int u = 0; u < 32; ++u) {
                        f32x4 wv = wp[u];
                        h0 += (double)(sE[u * 4 + 0] * wv[0]);
                        h1 += (double)(sE[u * 4 + 1] * wv[1]);
                        h2 += (double)(sE[u * 4 + 2] * wv[2]);
                        h3 += (double)(sE[u * 4 + 3] * wv[3]);
                    }
                    const float hv = (float)((h0 + h1) + (h2 + h3)) + b1[(size_t)bi * H_ + t];
                    shrow[t] = fmaxf(hv, 0.0f);
                }
                __syncthreads();
                if (t < D_) {
                    const f32x4* wp = (const f32x4*)(w2 + ((size_t)bi * D_ + t) * H_);
                    double s0 = 0, s1 = 0, s2 = 0, s3 = 0;
                    #pragma unroll 8
                    for (int u = 0; u < 64; ++u) {
                        f32x4 wv = wp[u];
                        s0 += (double)(shrow[u * 4 + 0] * wv[0]);
                        s1 += (double)(shrow[u * 4 + 1] * wv[1]);
                        s2 += (double)(shrow[u * 4 + 2] * wv[2]);
                        s3 += (double)(shrow[u * 4 + 3] * wv[3]);
                    }
                    sE[t] = (sE[t] + (float)((s0 + s1) + (s2 + s3))) + b2[(size_t)bi * D_ + t];
                }
                __syncthreads();
            }
            {
                double dp = 0.0;
                if (t < D_) {
                    const float e = sr[t] - sE[t];
                    const float e2 = e * e;
                    dp = (double)e2;
                    #pragma unroll
                    for (int s = 1; s < 64; s <<= 1) dp += __shfl_xor(dp, s);
                    if ((t & 63) == 0) sdd[t >> 6] = dp;
                }
            }
            __syncthreads();
            if (t == 0) {
                const float df = (float)(sdd[0] + sdd[1]);
                if (df < sbest) { sbest = df; sbidx = k; supd = 1; }
                else supd = 0;
            }
            __syncthreads();
            if (supd && t < D_) scsel[t] = sE[t];
            __syncthreads();
        }

        if (t == 0) out1[(size_t)n * M_ + m] = (float)sbidx;

        if (t < D_) {
            const float cs = scsel[t];
            out3[((size_t)m * N_ + n) * D_ + t] = cs;
            const float xnew = sxhat[t] + cs;
            sxhat[t] = xnew;
            if (m == M_ - 1) {
                const float zv = z[(size_t)n * D_ + t];
                out0[(size_t)n * D_ + t] = zv + (xnew - zv);
            }
        }
        __syncthreads();

        if (m < M_ - 1 && t < D_) {
            const f32x4* wp = (const f32x4*)(cp_w + ((size_t)((m + 1) * D_ + t)) * (2 * D_));
            double a0 = 0, a1 = 0, a2 = 0, a3 = 0;
            #pragma unroll 8
            for (int u = 0; u < 32; ++u) {
                f32x4 wv = wp[u];
                a0 += (double)(sxhat[u * 4 + 0] * wv[0]);
                a1 += (double)(sxhat[u * 4 + 1] * wv[1]);
                a2 += (double)(sxhat[u * 4 + 2] * wv[2]);
                a3 += (double)(sxhat[u * 4 + 3] * wv[3]);
            }
            sA[t] = (float)((a0 + a1) + (a2 + a3));
        }
        __syncthreads();
    }
    #undef CHI
    #undef CLO
    #undef CF
}

extern "C" void kernel_launch(void* const* d_in, const int* in_sizes, int n_in,
                              void* d_out, int out_size, void* d_ws, size_t ws_size,
                              hipStream_t stream) {
    const float* z       = (const float*)d_in[0];
    const float* base_cb = (const float*)d_in[1];
    const float* cp_w    = (const float*)d_in[2];
    const float* cp_b    = (const float*)d_in[3];
    const float* w1      = (const float*)d_in[4];
    const float* b1      = (const float*)d_in[5];
    const float* w2      = (const float*)d_in[6];
    const float* b2      = (const float*)d_in[7];

    float* out  = (float*)d_out;
    float* out0 = out;
    float* out1 = out0 + (size_t)N_ * D_;
    float* out2 = out1 + (size_t)N_ * M_;
    float* out3 = out2 + (size_t)M_ * N_ * D_;

    char* ws = (char*)d_ws;
    float*          Bb   = (float*)(ws + 0);
    unsigned short* w1pk = (unsigned short*)(ws + 524288);
    unsigned short* w2pk = (unsigned short*)(ws + 1048576);
    float*          Bbpk = (float*)(ws + 1572864);

    hipLaunchKernelGGL(precompute_Bb, dim3(M_ * K_), dim3(D_), 0, stream,
                       base_cb, cp_w, Bb, Bbpk);
    hipLaunchKernelGGL(convert_w, dim3(1024), dim3(256), 0, stream,
                       w1, w2, w1pk, w2pk);
    hipLaunchKernelGGL(mega_kernel, dim3(N_), dim3(256), 0, stream,
                       z, cp_w, cp_b, w1, b1, w2, b2, Bb, Bbpk,
                       w1pk, w2pk,
                       out0, out1, out2, out3);
}

// Round 16
// 878.219 us; speedup vs baseline: 1.2193x; 1.2193x over previous
//
#include <hip/hip_runtime.h>

#define N_ 1024
#define D_ 128
#define K_ 256
#define M_ 4
#define H_ 256
#define NB_ 2
#define KT_ 32
#define NTILE_ 8
#define EPS_ 0.12f
#define CHPAD 136
#define HPAD  264

typedef _Float16 half8 __attribute__((ext_vector_type(8)));
typedef __attribute__((ext_vector_type(8))) short short8;
typedef __attribute__((ext_vector_type(4))) float f32x4;
typedef __attribute__((ext_vector_type(16))) float f32x16;

__device__ inline float s2f(unsigned short s) {
    return (float)__builtin_bit_cast(_Float16, s);
}
__device__ inline unsigned short f2h(float x) {
    return __builtin_bit_cast(unsigned short, (_Float16)x);
}
__device__ inline void split2h(float x, unsigned short& hi, unsigned short& lo) {
    _Float16 h = (_Float16)x;
    _Float16 l = (_Float16)(x - (float)h);
    hi = __builtin_bit_cast(unsigned short, h);
    lo = __builtin_bit_cast(unsigned short, l);
}
__device__ inline f32x16 zero16() {
    f32x16 v;
    #pragma unroll
    for (int i = 0; i < 16; ++i) v[i] = 0.0f;
    return v;
}
// LDS-only barrier: wait LDS ops, sync, leave global loads in flight.
__device__ inline void lds_barrier() {
    asm volatile("s_waitcnt lgkmcnt(0)" ::: "memory");
    __builtin_amdgcn_sched_barrier(0);
    __builtin_amdgcn_s_barrier();
    __builtin_amdgcn_sched_barrier(0);
}

// ---------------------------------------------------------------------------
__global__ void precompute_Bb(const float* __restrict__ base_cb,
                              const float* __restrict__ cp_w,
                              float* __restrict__ Bb) {
    const int mk = blockIdx.x;
    const int m  = mk >> 8;
    const int d  = threadIdx.x;
    const float* cb = base_cb + (size_t)mk * D_;
    const float* wc = cp_w + ((size_t)(m * D_ + d)) * (2 * D_) + D_;
    double a0 = 0, a1 = 0, a2 = 0, a3 = 0;
    #pragma unroll
    for (int dp = 0; dp < D_; dp += 4) {
        a0 += (double)(cb[dp + 0] * wc[dp + 0]);
        a1 += (double)(cb[dp + 1] * wc[dp + 1]);
        a2 += (double)(cb[dp + 2] * wc[dp + 2]);
        a3 += (double)(cb[dp + 3] * wc[dp + 3]);
    }
    Bb[(size_t)mk * D_ + d] = (float)((a0 + a1) + (a2 + a3));
}

// ---------------------------------------------------------------------------
// Pack single-f16 weights into wave-coalesced fragment order.
// ---------------------------------------------------------------------------
__global__ void convert_w(const float* __restrict__ w1,
                          const float* __restrict__ w2,
                          unsigned short* __restrict__ w1pk,
                          unsigned short* __restrict__ w2pk) {
    const int i = blockIdx.x * blockDim.x + threadIdx.x;  // 0..262143
    {
        const int e    = i & 7;
        const int sel  = (i >> 3) & 1;
        const int j32  = (i >> 4) & 31;
        const int kt   = (i >> 9) & 7;
        const int jblk = (i >> 12) & 7;
        const int bi   = i >> 15;
        const int j = jblk * 32 + j32;
        const int d = kt * 16 + sel * 8 + e;
        w1pk[i] = f2h(w1[((size_t)(bi * H_ + j)) * D_ + d]);
    }
    {
        const int e    = i & 7;
        const int sel  = (i >> 3) & 1;
        const int d32  = (i >> 4) & 31;
        const int s    = (i >> 9) & 15;
        const int dblk = (i >> 13) & 3;
        const int bi   = i >> 15;
        const int d = dblk * 32 + d32;
        const int hc = s * 16 + sel * 8 + e;
        w2pk[i] = f2h(w2[((size_t)(bi * D_ + d)) * H_ + hc]);
    }
}

// ---------------------------------------------------------------------------
// mega kernel: one block per n; entire M-loop; KT=32 tiles so LDS < 40 KB
// -> 4 blocks/CU for barrier/latency overlap.
// ---------------------------------------------------------------------------
__launch_bounds__(256, 4)
__global__ void mega_kernel(const float* __restrict__ z,
                            const float* __restrict__ cp_w,
                            const float* __restrict__ cp_b,
                            const float* __restrict__ w1,
                            const float* __restrict__ b1,
                            const float* __restrict__ w2,
                            const float* __restrict__ b2,
                            const float* __restrict__ Bb,
                            const unsigned short* __restrict__ w1pk,
                            const unsigned short* __restrict__ w2pk,
                            float* __restrict__ out0,
                            float* __restrict__ out1,
                            float* __restrict__ out2,
                            float* __restrict__ out3) {
    __shared__ alignas(16) unsigned short sChi[KT_][CHPAD];
    __shared__ alignas(16) unsigned short sClo[KT_][CHPAD];
    __shared__ alignas(16) unsigned short sHh[KT_][HPAD];
    __shared__ alignas(16) float sA[D_], sxhat[D_], sr[D_], scb[D_];
    __shared__ alignas(16) float sdist[K_];
    __shared__ float sE[D_], scsel[D_];
    __shared__ float shrow[H_];
    __shared__ double sdd[2];
    __shared__ float smin, sbest;
    __shared__ int   sbidx, supd;

    const int n    = blockIdx.x;
    const int t    = threadIdx.x;
    const int wid  = t >> 6;
    const int lane = t & 63;
    const int l31  = lane & 31;
    const int hi   = lane >> 5;
    const int koff = hi * 8;
    const int loff = (l31 * 2 + hi) * 8;

    if (t < D_) { sxhat[t] = 0.0f; sA[t] = 0.0f; }
    __syncthreads();

    for (int m = 0; m < M_; ++m) {
        if (t < D_) {
            scb[t] = cp_b[m * D_ + t];
            const float rv = z[(size_t)n * D_ + t] - sxhat[t];
            sr[t] = rv;
            out2[((size_t)m * N_ + n) * D_ + t] = rv;
        }
        lds_barrier();

        // ================= fast path: 8 tiles of 32 codewords ==============
        for (int tile = 0; tile < NTILE_; ++tile) {
            const int k0 = tile * KT_;

            // ---- C init: C = (A + Bb) + cp_b, f16 hi/lo split ----
            {
                const int row  = t >> 3;          // 0..31
                const int dblk = (t & 7) * 16;    // 16 cols per thread
                const f32x4* bb4 = (const f32x4*)(Bb + ((size_t)(m * K_ + k0 + row)) * D_ + dblk);
                #pragma unroll
                for (int g = 0; g < 2; ++g) {
                    const f32x4 v0 = bb4[g * 2];
                    const f32x4 v1 = bb4[g * 2 + 1];
                    short8 hs, ls;
                    #pragma unroll
                    for (int x = 0; x < 8; ++x) {
                        const int d = dblk + g * 8 + x;
                        const float bv = (x < 4) ? v0[x] : v1[x - 4];
                        unsigned short ch, cl;
                        split2h((sA[d] + bv) + scb[d], ch, cl);
                        hs[x] = (short)ch;
                        ls[x] = (short)cl;
                    }
                    *(short8*)&sChi[row][dblk + g * 8] = hs;
                    *(short8*)&sClo[row][dblk + g * 8] = ls;
                }
            }
            lds_barrier();

            for (int i = 0; i < NB_; ++i) {
                const int bi = m * NB_ + i;

                // ---- GEMM1 (2-pass): h = relu(C @ W1^T + b1) ----
                half8 g2w[16];
                {
                    const int j0 = wid * 32 + l31;
                    const unsigned short* pA = w1pk + ((size_t)((bi * 8 + wid) * 8)) * 512 + loff;
                    const unsigned short* pB = w1pk + ((size_t)((bi * 8 + wid + 4) * 8)) * 512 + loff;
                    half8 wA[8], wB[8];
                    #pragma unroll
                    for (int kt = 0; kt < 8; ++kt) {
                        wA[kt] = *(const half8*)(pA + kt * 512);
                        wB[kt] = *(const half8*)(pB + kt * 512);
                    }
                    f32x16 aA = zero16(), aB = zero16();
                    #pragma unroll
                    for (int kt = 0; kt < 8; ++kt) {
                        half8 ah = *(const half8*)&sChi[l31][kt * 16 + koff];
                        half8 al = *(const half8*)&sClo[l31][kt * 16 + koff];
                        aA = __builtin_amdgcn_mfma_f32_32x32x16_f16(ah, wA[kt], aA, 0, 0, 0);
                        aB = __builtin_amdgcn_mfma_f32_32x32x16_f16(ah, wB[kt], aB, 0, 0, 0);
                        aA = __builtin_amdgcn_mfma_f32_32x32x16_f16(al, wA[kt], aA, 0, 0, 0);
                        aB = __builtin_amdgcn_mfma_f32_32x32x16_f16(al, wB[kt], aB, 0, 0, 0);
                    }
                    // prefetch GEMM2 weights (survive the LDS barrier)
                    {
                        const unsigned short* pd =
                            w2pk + ((size_t)((bi * 4 + wid) * 16)) * 512 + loff;
                        #pragma unroll
                        for (int s = 0; s < 16; ++s)
                            g2w[s] = *(const half8*)(pd + s * 512);
                    }
                    const float b1A = b1[(size_t)bi * H_ + j0];
                    const float b1B = b1[(size_t)bi * H_ + j0 + 128];
                    #pragma unroll
                    for (int reg = 0; reg < 16; ++reg) {
                        const int krow = (reg & 3) + 8 * (reg >> 2) + 4 * hi;
                        sHh[krow][j0]       = f2h(fmaxf(aA[reg] + b1A, 0.0f));
                        sHh[krow][j0 + 128] = f2h(fmaxf(aB[reg] + b1B, 0.0f));
                    }
                }
                lds_barrier();

                // ---- GEMM2 (1-pass, full H): C = (C + h @ W2^T) + b2 ----
                {
                    const int d = wid * 32 + l31;
                    f32x16 c0a = zero16(), c0b = zero16();
                    #pragma unroll
                    for (int s = 0; s < 16; s += 2) {
                        half8 h0e = *(const half8*)&sHh[l31][s * 16 + koff];
                        half8 h0o = *(const half8*)&sHh[l31][(s + 1) * 16 + koff];
                        c0a = __builtin_amdgcn_mfma_f32_32x32x16_f16(h0e, g2w[s], c0a, 0, 0, 0);
                        c0b = __builtin_amdgcn_mfma_f32_32x32x16_f16(h0o, g2w[s + 1], c0b, 0, 0, 0);
                    }
                    const float b2v = b2[(size_t)bi * D_ + d];
                    #pragma unroll
                    for (int reg = 0; reg < 16; ++reg) {
                        const int krow = (reg & 3) + 8 * (reg >> 2) + 4 * hi;
                        const float cvo = s2f(sChi[krow][d]) + s2f(sClo[krow][d]);
                        const float cv  = (cvo + (c0a[reg] + c0b[reg])) + b2v;
                        unsigned short ch, cl;
                        split2h(cv, ch, cl);
                        sChi[krow][d] = ch;
                        sClo[krow][d] = cl;
                    }
                }
                lds_barrier();
            }

            // ---- fast dists for this tile ----
            if (t < 128) {
                const int row = t >> 2, seg = t & 3;
                float qa = 0.f;
                #pragma unroll
                for (int dd = 0; dd < 32; ++dd) {
                    const int d = seg * 32 + dd;
                    const float cv = s2f(sChi[row][d]) + s2f(sClo[row][d]);
                    const float e = sr[d] - cv;
                    qa = fmaf(e, e, qa);
                }
                qa += __shfl_xor(qa, 1);
                qa += __shfl_xor(qa, 2);
                if (seg == 0) sdist[k0 + row] = qa;
            }
            lds_barrier();
        }

        // ================= refine: serial exact f64 candidates =============
        if (t < 64) {
            float bv = fminf(fminf(sdist[t], sdist[t + 64]),
                             fminf(sdist[t + 128], sdist[t + 192]));
            #pragma unroll
            for (int s = 1; s < 64; s <<= 1) bv = fminf(bv, __shfl_xor(bv, s));
            if (t == 0) { smin = bv; sbest = 1e30f; sbidx = 0; }
        }
        __syncthreads();
        const float thr = smin + EPS_;

        for (int k = 0; k < K_; ++k) {
            if (sdist[k] > thr) continue;
            if (t < D_)
                sE[t] = (sA[t] + Bb[((size_t)(m * K_ + k)) * D_ + t]) + scb[t];
            __syncthreads();
            for (int i = 0; i < NB_; ++i) {
                const int bi = m * NB_ + i;
                {
                    const f32x4* wp = (const f32x4*)(w1 + ((size_t)bi * H_ + t) * D_);
                    double h0 = 0, h1 = 0, h2 = 0, h3 = 0;
                    #pragma unroll 8
                    for (int u = 0; u < 32; ++u) {
                        f32x4 wv = wp[u];
                        h0 += (double)(sE[u * 4 + 0] * wv[0]);
                        h1 += (double)(sE[u * 4 + 1] * wv[1]);
                        h2 += (double)(sE[u * 4 + 2] * wv[2]);
                        h3 += (double)(sE[u * 4 + 3] * wv[3]);
                    }
                    const float hv = (float)((h0 + h1) + (h2 + h3)) + b1[(size_t)bi * H_ + t];
                    shrow[t] = fmaxf(hv, 0.0f);
                }
                __syncthreads();
                if (t < D_) {
                    const f32x4* wp = (const f32x4*)(w2 + ((size_t)bi * D_ + t) * H_);
                    double s0 = 0, s1 = 0, s2 = 0, s3 = 0;
                    #pragma unroll 8
                    for (int u = 0; u < 64; ++u) {
                        f32x4 wv = wp[u];
                        s0 += (double)(shrow[u * 4 + 0] * wv[0]);
                        s1 += (double)(shrow[u * 4 + 1] * wv[1]);
                        s2 += (double)(shrow[u * 4 + 2] * wv[2]);
                        s3 += (double)(shrow[u * 4 + 3] * wv[3]);
                    }
                    sE[t] = (sE[t] + (float)((s0 + s1) + (s2 + s3))) + b2[(size_t)bi * D_ + t];
                }
                __syncthreads();
            }
            {
                double dp = 0.0;
                if (t < D_) {
                    const float e = sr[t] - sE[t];
                    const float e2 = e * e;
                    dp = (double)e2;
                    #pragma unroll
                    for (int s = 1; s < 64; s <<= 1) dp += __shfl_xor(dp, s);
                    if ((t & 63) == 0) sdd[t >> 6] = dp;
                }
            }
            __syncthreads();
            if (t == 0) {
                const float df = (float)(sdd[0] + sdd[1]);
                if (df < sbest) { sbest = df; sbidx = k; supd = 1; }
                else supd = 0;
            }
            __syncthreads();
            if (supd && t < D_) scsel[t] = sE[t];
            __syncthreads();
        }

        if (t == 0) out1[(size_t)n * M_ + m] = (float)sbidx;

        if (t < D_) {
            const float cs = scsel[t];
            out3[((size_t)m * N_ + n) * D_ + t] = cs;
            const float xnew = sxhat[t] + cs;
            sxhat[t] = xnew;
            if (m == M_ - 1) {
                const float zv = z[(size_t)n * D_ + t];
                out0[(size_t)n * D_ + t] = zv + (xnew - zv);
            }
        }
        __syncthreads();

        if (m < M_ - 1 && t < D_) {
            const f32x4* wp = (const f32x4*)(cp_w + ((size_t)((m + 1) * D_ + t)) * (2 * D_));
            double a0 = 0, a1 = 0, a2 = 0, a3 = 0;
            #pragma unroll 8
            for (int u = 0; u < 32; ++u) {
                f32x4 wv = wp[u];
                a0 += (double)(sxhat[u * 4 + 0] * wv[0]);
                a1 += (double)(sxhat[u * 4 + 1] * wv[1]);
                a2 += (double)(sxhat[u * 4 + 2] * wv[2]);
                a3 += (double)(sxhat[u * 4 + 3] * wv[3]);
            }
            sA[t] = (float)((a0 + a1) + (a2 + a3));
        }
        __syncthreads();
    }
}

extern "C" void kernel_launch(void* const* d_in, const int* in_sizes, int n_in,
                              void* d_out, int out_size, void* d_ws, size_t ws_size,
                              hipStream_t stream) {
    const float* z       = (const float*)d_in[0];
    const float* base_cb = (const float*)d_in[1];
    const float* cp_w    = (const float*)d_in[2];
    const float* cp_b    = (const float*)d_in[3];
    const float* w1      = (const float*)d_in[4];
    const float* b1      = (const float*)d_in[5];
    const float* w2      = (const float*)d_in[6];
    const float* b2      = (const float*)d_in[7];

    float* out  = (float*)d_out;
    float* out0 = out;
    float* out1 = out0 + (size_t)N_ * D_;
    float* out2 = out1 + (size_t)N_ * M_;
    float* out3 = out2 + (size_t)M_ * N_ * D_;

    char* ws = (char*)d_ws;
    float*          Bb   = (float*)(ws + 0);
    unsigned short* w1pk = (unsigned short*)(ws + 524288);
    unsigned short* w2pk = (unsigned short*)(ws + 1048576);

    hipLaunchKernelGGL(precompute_Bb, dim3(M_ * K_), dim3(D_), 0, stream,
                       base_cb, cp_w, Bb);
    hipLaunchKernelGGL(convert_w, dim3(1024), dim3(256), 0, stream,
                       w1, w2, w1pk, w2pk);
    hipLaunchKernelGGL(mega_kernel, dim3(N_), dim3(256), 0, stream,
                       z, cp_w, cp_b, w1, b1, w2, b2, Bb,
                       w1pk, w2pk,
                       out0, out1, out2, out3);
}

// Round 17
// 850.580 us; speedup vs baseline: 1.2590x; 1.0325x over previous
//
#include <hip/hip_runtime.h>

#define N_ 1024
#define D_ 128
#define K_ 256
#define M_ 4
#define H_ 256
#define NB_ 2
#define KT_ 32
#define NTILE_ 8
#define EPS_ 0.08f
#define CHPAD 136
#define CFS 132
#define HPAD  264

typedef _Float16 half8 __attribute__((ext_vector_type(8)));
typedef __attribute__((ext_vector_type(8))) short short8;
typedef __attribute__((ext_vector_type(4))) float f32x4;
typedef __attribute__((ext_vector_type(16))) float f32x16;

__device__ inline float s2f(unsigned short s) {
    return (float)__builtin_bit_cast(_Float16, s);
}
__device__ inline unsigned short f2h(float x) {
    return __builtin_bit_cast(unsigned short, (_Float16)x);
}
__device__ inline void split2h(float x, unsigned short& hi, unsigned short& lo) {
    _Float16 h = (_Float16)x;
    _Float16 l = (_Float16)(x - (float)h);
    hi = __builtin_bit_cast(unsigned short, h);
    lo = __builtin_bit_cast(unsigned short, l);
}
__device__ inline f32x16 zero16() {
    f32x16 v;
    #pragma unroll
    for (int i = 0; i < 16; ++i) v[i] = 0.0f;
    return v;
}
// LDS-only barrier: wait LDS ops, sync, leave global loads in flight.
__device__ inline void lds_barrier() {
    asm volatile("s_waitcnt lgkmcnt(0)" ::: "memory");
    __builtin_amdgcn_sched_barrier(0);
    __builtin_amdgcn_s_barrier();
    __builtin_amdgcn_sched_barrier(0);
}

// ---------------------------------------------------------------------------
__global__ void precompute_Bb(const float* __restrict__ base_cb,
                              const float* __restrict__ cp_w,
                              float* __restrict__ Bb) {
    const int mk = blockIdx.x;
    const int m  = mk >> 8;
    const int d  = threadIdx.x;
    const float* cb = base_cb + (size_t)mk * D_;
    const float* wc = cp_w + ((size_t)(m * D_ + d)) * (2 * D_) + D_;
    double a0 = 0, a1 = 0, a2 = 0, a3 = 0;
    #pragma unroll
    for (int dp = 0; dp < D_; dp += 4) {
        a0 += (double)(cb[dp + 0] * wc[dp + 0]);
        a1 += (double)(cb[dp + 1] * wc[dp + 1]);
        a2 += (double)(cb[dp + 2] * wc[dp + 2]);
        a3 += (double)(cb[dp + 3] * wc[dp + 3]);
    }
    Bb[(size_t)mk * D_ + d] = (float)((a0 + a1) + (a2 + a3));
}

// ---------------------------------------------------------------------------
// Pack single-f16 weights into wave-coalesced fragment order.
// ---------------------------------------------------------------------------
__global__ void convert_w(const float* __restrict__ w1,
                          const float* __restrict__ w2,
                          unsigned short* __restrict__ w1pk,
                          unsigned short* __restrict__ w2pk) {
    const int i = blockIdx.x * blockDim.x + threadIdx.x;  // 0..262143
    {
        const int e    = i & 7;
        const int sel  = (i >> 3) & 1;
        const int j32  = (i >> 4) & 31;
        const int kt   = (i >> 9) & 7;
        const int jblk = (i >> 12) & 7;
        const int bi   = i >> 15;
        const int j = jblk * 32 + j32;
        const int d = kt * 16 + sel * 8 + e;
        w1pk[i] = f2h(w1[((size_t)(bi * H_ + j)) * D_ + d]);
    }
    {
        const int e    = i & 7;
        const int sel  = (i >> 3) & 1;
        const int d32  = (i >> 4) & 31;
        const int s    = (i >> 9) & 15;
        const int dblk = (i >> 13) & 3;
        const int bi   = i >> 15;
        const int d = dblk * 32 + d32;
        const int hc = s * 16 + sel * 8 + e;
        w2pk[i] = f2h(w2[((size_t)(bi * D_ + d)) * H_ + hc]);
    }
}

// ---------------------------------------------------------------------------
// mega kernel: one block per n; entire M-loop; KT=32 tiles, 4 blocks/CU.
// Last-NB C-update seeds MFMA acc with pre-read old C and writes f32 C.
// ---------------------------------------------------------------------------
__launch_bounds__(256, 4)
__global__ void mega_kernel(const float* __restrict__ z,
                            const float* __restrict__ cp_w,
                            const float* __restrict__ cp_b,
                            const float* __restrict__ w1,
                            const float* __restrict__ b1,
                            const float* __restrict__ w2,
                            const float* __restrict__ b2,
                            const float* __restrict__ Bb,
                            const unsigned short* __restrict__ w1pk,
                            const unsigned short* __restrict__ w2pk,
                            float* __restrict__ out0,
                            float* __restrict__ out1,
                            float* __restrict__ out2,
                            float* __restrict__ out3) {
    __shared__ alignas(16) unsigned short sCbuf[2 * KT_ * CHPAD];  // split C OR f32 C
    __shared__ alignas(16) unsigned short sHh[KT_][HPAD];
    __shared__ alignas(16) float sA[D_], sxhat[D_], sr[D_], scb[D_];
    __shared__ alignas(16) float sdist[K_];
    __shared__ float sE[D_], scsel[D_];
    __shared__ float shrow[H_];
    __shared__ double sdd[2];
    __shared__ float smin;
    __shared__ float sbest;
    __shared__ int   sbidx, supd;

    #define CHI(r, c) (sCbuf[(r) * CHPAD + (c)])
    #define CLO(r, c) (sCbuf[KT_ * CHPAD + (r) * CHPAD + (c)])
    #define CFC(r, c) (((float*)sCbuf)[(r) * CFS + (c)])

    const int n    = blockIdx.x;
    const int t    = threadIdx.x;
    const int wid  = t >> 6;
    const int lane = t & 63;
    const int l31  = lane & 31;
    const int hi   = lane >> 5;
    const int koff = hi * 8;
    const int loff = (l31 * 2 + hi) * 8;
    const int dcol = wid * 32 + l31;

    if (t < D_) { sxhat[t] = 0.0f; sA[t] = 0.0f; }
    __syncthreads();

    for (int m = 0; m < M_; ++m) {
        if (t < D_) {
            scb[t] = cp_b[m * D_ + t];
            const float rv = z[(size_t)n * D_ + t] - sxhat[t];
            sr[t] = rv;
            out2[((size_t)m * N_ + n) * D_ + t] = rv;
        }
        lds_barrier();

        // ================= fast path: 8 tiles of 32 codewords ==============
        for (int tile = 0; tile < NTILE_; ++tile) {
            const int k0 = tile * KT_;

            // ---- C init: C = (A + Bb) + cp_b, f16 hi/lo split ----
            {
                const int row  = t >> 3;          // 0..31
                const int dblk = (t & 7) * 16;    // 16 cols per thread
                const f32x4* bb4 = (const f32x4*)(Bb + ((size_t)(m * K_ + k0 + row)) * D_ + dblk);
                #pragma unroll
                for (int g = 0; g < 2; ++g) {
                    const f32x4 v0 = bb4[g * 2];
                    const f32x4 v1 = bb4[g * 2 + 1];
                    short8 hs, ls;
                    #pragma unroll
                    for (int x = 0; x < 8; ++x) {
                        const int d = dblk + g * 8 + x;
                        const float bv = (x < 4) ? v0[x] : v1[x - 4];
                        unsigned short ch, cl;
                        split2h((sA[d] + bv) + scb[d], ch, cl);
                        hs[x] = (short)ch;
                        ls[x] = (short)cl;
                    }
                    *(short8*)&CHI(row, dblk + g * 8) = hs;
                    *(short8*)&CLO(row, dblk + g * 8) = ls;
                }
            }
            lds_barrier();

            for (int i = 0; i < NB_; ++i) {
                const int bi = m * NB_ + i;
                f32x16 cvo = zero16();   // pre-read old C (last NB only)

                // ---- GEMM1 (2-pass): h = relu(C @ W1^T + b1) ----
                half8 g2w[16];
                {
                    const int j0 = wid * 32 + l31;
                    const unsigned short* pA = w1pk + ((size_t)((bi * 8 + wid) * 8)) * 512 + loff;
                    const unsigned short* pB = w1pk + ((size_t)((bi * 8 + wid + 4) * 8)) * 512 + loff;
                    half8 wA[8], wB[8];
                    #pragma unroll
                    for (int kt = 0; kt < 8; ++kt) {
                        wA[kt] = *(const half8*)(pA + kt * 512);
                        wB[kt] = *(const half8*)(pB + kt * 512);
                    }
                    f32x16 aA = zero16(), aB = zero16();
                    #pragma unroll
                    for (int kt = 0; kt < 8; ++kt) {
                        half8 ah = *(const half8*)&CHI(l31, kt * 16 + koff);
                        half8 al = *(const half8*)&CLO(l31, kt * 16 + koff);
                        aA = __builtin_amdgcn_mfma_f32_32x32x16_f16(ah, wA[kt], aA, 0, 0, 0);
                        aB = __builtin_amdgcn_mfma_f32_32x32x16_f16(ah, wB[kt], aB, 0, 0, 0);
                        aA = __builtin_amdgcn_mfma_f32_32x32x16_f16(al, wA[kt], aA, 0, 0, 0);
                        aB = __builtin_amdgcn_mfma_f32_32x32x16_f16(al, wB[kt], aB, 0, 0, 0);
                    }
                    // prefetch GEMM2 weights (survive the LDS barrier)
                    {
                        const unsigned short* pd =
                            w2pk + ((size_t)((bi * 4 + wid) * 16)) * 512 + loff;
                        #pragma unroll
                        for (int s = 0; s < 16; ++s)
                            g2w[s] = *(const half8*)(pd + s * 512);
                    }
                    const float b1A = b1[(size_t)bi * H_ + j0];
                    const float b1B = b1[(size_t)bi * H_ + j0 + 128];
                    #pragma unroll
                    for (int reg = 0; reg < 16; ++reg) {
                        const int krow = (reg & 3) + 8 * (reg >> 2) + 4 * hi;
                        sHh[krow][j0]       = f2h(fmaxf(aA[reg] + b1A, 0.0f));
                        sHh[krow][j0 + 128] = f2h(fmaxf(aB[reg] + b1B, 0.0f));
                    }
                    // pre-read old C for the last NB (reads complete before the
                    // barrier; GEMM2 epilogue then overwrites the region as f32)
                    if (i == NB_ - 1) {
                        #pragma unroll
                        for (int reg = 0; reg < 16; ++reg) {
                            const int krow = (reg & 3) + 8 * (reg >> 2) + 4 * hi;
                            cvo[reg] = s2f(CHI(krow, dcol)) + s2f(CLO(krow, dcol));
                        }
                    }
                }
                lds_barrier();

                // ---- GEMM2 (1-pass): C = (C + h @ W2^T) + b2 ----
                {
                    f32x16 c0a = (i == NB_ - 1) ? cvo : zero16();
                    f32x16 c0b = zero16();
                    #pragma unroll
                    for (int s = 0; s < 16; s += 2) {
                        half8 h0e = *(const half8*)&sHh[l31][s * 16 + koff];
                        half8 h0o = *(const half8*)&sHh[l31][(s + 1) * 16 + koff];
                        c0a = __builtin_amdgcn_mfma_f32_32x32x16_f16(h0e, g2w[s], c0a, 0, 0, 0);
                        c0b = __builtin_amdgcn_mfma_f32_32x32x16_f16(h0o, g2w[s + 1], c0b, 0, 0, 0);
                    }
                    const float b2v = b2[(size_t)bi * D_ + dcol];
                    if (i < NB_ - 1) {
                        #pragma unroll
                        for (int reg = 0; reg < 16; ++reg) {
                            const int krow = (reg & 3) + 8 * (reg >> 2) + 4 * hi;
                            const float cvr = s2f(CHI(krow, dcol)) + s2f(CLO(krow, dcol));
                            const float cv  = (cvr + (c0a[reg] + c0b[reg])) + b2v;
                            unsigned short ch, cl;
                            split2h(cv, ch, cl);
                            CHI(krow, dcol) = ch;
                            CLO(krow, dcol) = cl;
                        }
                    } else {
                        #pragma unroll
                        for (int reg = 0; reg < 16; ++reg) {
                            const int krow = (reg & 3) + 8 * (reg >> 2) + 4 * hi;
                            CFC(krow, dcol) = (c0a[reg] + c0b[reg]) + b2v;
                        }
                    }
                }
                lds_barrier();
            }

            // ---- fast dists (256 threads, f32 vector reads) ----
            {
                const int row = t >> 3, seg = t & 7, db = seg * 16;
                float qa = 0.f;
                #pragma unroll
                for (int g = 0; g < 4; ++g) {
                    const f32x4 cv = *(const f32x4*)&CFC(row, db + g * 4);
                    const f32x4 rv = *(const f32x4*)&sr[db + g * 4];
                    #pragma unroll
                    for (int x = 0; x < 4; ++x) {
                        const float e = rv[x] - cv[x];
                        qa = fmaf(e, e, qa);
                    }
                }
                qa += __shfl_xor(qa, 1);
                qa += __shfl_xor(qa, 2);
                qa += __shfl_xor(qa, 4);
                if (seg == 0) sdist[k0 + row] = qa;
            }
            lds_barrier();
        }

        // ================= refine: exact f64 candidates =====================
        if (t < 64) {
            float bv = fminf(fminf(sdist[t], sdist[t + 64]),
                             fminf(sdist[t + 128], sdist[t + 192]));
            #pragma unroll
            for (int s = 1; s < 64; s <<= 1) bv = fminf(bv, __shfl_xor(bv, s));
            if (t == 0) { smin = bv; sbest = 1e30f; sbidx = 0; }
        }
        __syncthreads();
        const float thr = smin + EPS_;
        const int flag = (sdist[t] <= thr) ? 1 : 0;
        const int cnt = __syncthreads_count(flag);

        if (cnt == 1) {
            // single candidate: recompute its row exactly (needed for outputs)
            if (flag) sbidx = t;
            __syncthreads();
            const int k = sbidx;
            if (t < D_)
                sE[t] = (sA[t] + Bb[((size_t)(m * K_ + k)) * D_ + t]) + scb[t];
            __syncthreads();
            for (int i = 0; i < NB_; ++i) {
                const int bi = m * NB_ + i;
                {
                    const f32x4* wp = (const f32x4*)(w1 + ((size_t)bi * H_ + t) * D_);
                    double h0 = 0, h1 = 0, h2 = 0, h3 = 0;
                    #pragma unroll 8
                    for (int u = 0; u < 32; ++u) {
                        f32x4 wv = wp[u];
                        h0 += (double)(sE[u * 4 + 0] * wv[0]);
                        h1 += (double)(sE[u * 4 + 1] * wv[1]);
                        h2 += (double)(sE[u * 4 + 2] * wv[2]);
                        h3 += (double)(sE[u * 4 + 3] * wv[3]);
                    }
                    const float hv = (float)((h0 + h1) + (h2 + h3)) + b1[(size_t)bi * H_ + t];
                    shrow[t] = fmaxf(hv, 0.0f);
                }
                __syncthreads();
                if (t < D_) {
                    const f32x4* wp = (const f32x4*)(w2 + ((size_t)bi * D_ + t) * H_);
                    double s0 = 0, s1 = 0, s2 = 0, s3 = 0;
                    #pragma unroll 8
                    for (int u = 0; u < 64; ++u) {
                        f32x4 wv = wp[u];
                        s0 += (double)(shrow[u * 4 + 0] * wv[0]);
                        s1 += (double)(shrow[u * 4 + 1] * wv[1]);
                        s2 += (double)(shrow[u * 4 + 2] * wv[2]);
                        s3 += (double)(shrow[u * 4 + 3] * wv[3]);
                    }
                    sE[t] = (sE[t] + (float)((s0 + s1) + (s2 + s3))) + b2[(size_t)bi * D_ + t];
                }
                __syncthreads();
            }
            if (t < D_) scsel[t] = sE[t];
            __syncthreads();
        } else {
            for (int k = 0; k < K_; ++k) {
                if (sdist[k] > thr) continue;
                if (t < D_)
                    sE[t] = (sA[t] + Bb[((size_t)(m * K_ + k)) * D_ + t]) + scb[t];
                __syncthreads();
                for (int i = 0; i < NB_; ++i) {
                    const int bi = m * NB_ + i;
                    {
                        const f32x4* wp = (const f32x4*)(w1 + ((size_t)bi * H_ + t) * D_);
                        double h0 = 0, h1 = 0, h2 = 0, h3 = 0;
                        #pragma unroll 8
                        for (int u = 0; u < 32; ++u) {
                            f32x4 wv = wp[u];
                            h0 += (double)(sE[u * 4 + 0] * wv[0]);
                            h1 += (double)(sE[u * 4 + 1] * wv[1]);
                            h2 += (double)(sE[u * 4 + 2] * wv[2]);
                            h3 += (double)(sE[u * 4 + 3] * wv[3]);
                        }
                        const float hv = (float)((h0 + h1) + (h2 + h3)) + b1[(size_t)bi * H_ + t];
                        shrow[t] = fmaxf(hv, 0.0f);
                    }
                    __syncthreads();
                    if (t < D_) {
                        const f32x4* wp = (const f32x4*)(w2 + ((size_t)bi * D_ + t) * H_);
                        double s0 = 0, s1 = 0, s2 = 0, s3 = 0;
                        #pragma unroll 8
                        for (int u = 0; u < 64; ++u) {
                            f32x4 wv = wp[u];
                            s0 += (double)(shrow[u * 4 + 0] * wv[0]);
                            s1 += (double)(shrow[u * 4 + 1] * wv[1]);
                            s2 += (double)(shrow[u * 4 + 2] * wv[2]);
                            s3 += (double)(shrow[u * 4 + 3] * wv[3]);
                        }
                        sE[t] = (sE[t] + (float)((s0 + s1) + (s2 + s3))) + b2[(size_t)bi * D_ + t];
                    }
                    __syncthreads();
                }
                {
                    double dp = 0.0;
                    if (t < D_) {
                        const float e = sr[t] - sE[t];
                        const float e2 = e * e;
                        dp = (double)e2;
                        #pragma unroll
                        for (int s = 1; s < 64; s <<= 1) dp += __shfl_xor(dp, s);
                        if ((t & 63) == 0) sdd[t >> 6] = dp;
                    }
                }
                __syncthreads();
                if (t == 0) {
                    const float df = (float)(sdd[0] + sdd[1]);
                    if (df < sbest) { sbest = df; sbidx = k; supd = 1; }
                    else supd = 0;
                }
                __syncthreads();
                if (supd && t < D_) scsel[t] = sE[t];
                __syncthreads();
            }
        }

        if (t == 0) out1[(size_t)n * M_ + m] = (float)sbidx;

        if (t < D_) {
            const float cs = scsel[t];
            out3[((size_t)m * N_ + n) * D_ + t] = cs;
            const float xnew = sxhat[t] + cs;
            sxhat[t] = xnew;
            if (m == M_ - 1) {
                const float zv = z[(size_t)n * D_ + t];
                out0[(size_t)n * D_ + t] = zv + (xnew - zv);
            }
        }
        __syncthreads();

        if (m < M_ - 1 && t < D_) {
            const f32x4* wp = (const f32x4*)(cp_w + ((size_t)((m + 1) * D_ + t)) * (2 * D_));
            double a0 = 0, a1 = 0, a2 = 0, a3 = 0;
            #pragma unroll 8
            for (int u = 0; u < 32; ++u) {
                f32x4 wv = wp[u];
                a0 += (double)(sxhat[u * 4 + 0] * wv[0]);
                a1 += (double)(sxhat[u * 4 + 1] * wv[1]);
                a2 += (double)(sxhat[u * 4 + 2] * wv[2]);
                a3 += (double)(sxhat[u * 4 + 3] * wv[3]);
            }
            sA[t] = (float)((a0 + a1) + (a2 + a3));
        }
        __syncthreads();
    }
    #undef CHI
    #undef CLO
    #undef CFC
}

extern "C" void kernel_launch(void* const* d_in, const int* in_sizes, int n_in,
                              void* d_out, int out_size, void* d_ws, size_t ws_size,
                              hipStream_t stream) {
    const float* z       = (const float*)d_in[0];
    const float* base_cb = (const float*)d_in[1];
    const float* cp_w    = (const float*)d_in[2];
    const float* cp_b    = (const float*)d_in[3];
    const float* w1      = (const float*)d_in[4];
    const float* b1      = (const float*)d_in[5];
    const float* w2      = (const float*)d_in[6];
    const float* b2      = (const float*)d_in[7];

    float* out  = (float*)d_out;
    float* out0 = out;
    float* out1 = out0 + (size_t)N_ * D_;
    float* out2 = out1 + (size_t)N_ * M_;
    float* out3 = out2 + (size_t)M_ * N_ * D_;

    char* ws = (char*)d_ws;
    float*          Bb   = (float*)(ws + 0);
    unsigned short* w1pk = (unsigned short*)(ws + 524288);
    unsigned short* w2pk = (unsigned short*)(ws + 1048576);

    hipLaunchKernelGGL(precompute_Bb, dim3(M_ * K_), dim3(D_), 0, stream,
                       base_cb, cp_w, Bb);
    hipLaunchKernelGGL(convert_w, dim3(1024), dim3(256), 0, stream,
                       w1, w2, w1pk, w2pk);
    hipLaunchKernelGGL(mega_kernel, dim3(N_), dim3(256), 0, stream,
                       z, cp_w, cp_b, w1, b1, w2, b2, Bb,
                       w1pk, w2pk,
                       out0, out1, out2, out3);
}